// Round 4
// baseline (241.390 us; speedup 1.0000x reference)
//
#include <hip/hip_runtime.h>
#include <stdint.h>

#define AS1 __attribute__((address_space(1)))
#define AS3 __attribute__((address_space(3)))

typedef int v4i __attribute__((ext_vector_type(4)));

// Problem constants (from reference)
constexpr int G = 7, B = 8, M = 512, N = 512, K = 1024;
constexpr int GBn = G * B;                       // 56
// X_ZP = -66, Y_ZP = 160 (hardcoded in reference)
// With y' = y - 128:  sum (x-X)(y-Y) = dot(x,y') - 32*rowsum_x + 66*colsum_y' - 2162688

// ws layout
constexpr size_t X8_BYTES = (size_t)GBn * M * K; // 29,360,128  packed x int8
constexpr size_t YT_BYTES = (size_t)B * N * K;   //  4,194,304  y transposed [b][n][k] int8 (y-128)
constexpr size_t RS_CNT   = (size_t)GBn * M;     // 28,672 rowsums
constexpr size_t CS_CNT   = (size_t)B * N;       //  4,096 colsums
constexpr size_t WS_NEEDED = X8_BYTES + YT_BYTES + RS_CNT * 4 + CS_CNT * 4;

// ---------------------------------------------------------------------------
// K1: transpose + pack y:  y[b][k][n] (int32, 0..255)  ->  yt[b][n][k] (int8, y-128)
// 64x64 tiles through LDS. Grid: (N/64, K/64, B), block 256.
// ---------------------------------------------------------------------------
__global__ __launch_bounds__(256) void transpose_pack_y(const int* __restrict__ y,
                                                        signed char* __restrict__ yt) {
    __shared__ unsigned char tile[64][80];       // 80 = 5*16: 16B-aligned rows, odd 16-bank phase
    int n0 = blockIdx.x * 64;
    int k0 = blockIdx.y * 64;
    int b  = blockIdx.z;
    int t  = threadIdx.x;

    // phase 1: coalesced read along n, pack low bytes (^0x80 == y-128 as i8), 16B to LDS
    int r  = t >> 2;                              // k-local 0..63
    int c0 = (t & 3) * 16;                        // n-local byte offset
    const int* src = y + ((size_t)b * K + k0 + r) * N + n0 + c0;
    uint32_t p[4];
#pragma unroll
    for (int q = 0; q < 4; ++q) {
        int4 v = ((const int4*)src)[q];
        p[q] =  (uint32_t)((v.x & 255) ^ 128)
             | ((uint32_t)((v.y & 255) ^ 128) << 8)
             | ((uint32_t)((v.z & 255) ^ 128) << 16)
             | ((uint32_t)((v.w & 255) ^ 128) << 24);
    }
    *(uint4*)&tile[r][c0] = make_uint4(p[0], p[1], p[2], p[3]);
    __syncthreads();

    // phase 2: gather a column of 16 k-bytes per thread, write 16B contiguous in k
    int nl = t >> 2;                              // n-local 0..63
    int kc = (t & 3) * 16;                        // k-local byte offset
    uint32_t q[4];
#pragma unroll
    for (int w = 0; w < 4; ++w) {
        uint32_t b0 = tile[kc + w * 4 + 0][nl];
        uint32_t b1 = tile[kc + w * 4 + 1][nl];
        uint32_t b2 = tile[kc + w * 4 + 2][nl];
        uint32_t b3 = tile[kc + w * 4 + 3][nl];
        q[w] = b0 | (b1 << 8) | (b2 << 16) | (b3 << 24);
    }
    *(uint4*)(yt + ((size_t)b * N + n0 + nl) * K + k0 + kc) = make_uint4(q[0], q[1], q[2], q[3]);
}

// ---------------------------------------------------------------------------
// K2: pack x int32 -> int8 + rowsum(x);  plus colsum(y') from yt.
// One wave per 1024-elem row. Rows 0..28671 = x rows; 28672..32767 = yt rows.
// Grid: 8192 blocks x 256 (4 waves, 4 rows/block).
// ---------------------------------------------------------------------------
__device__ __forceinline__ int wave_reduce_sum(int v) {
#pragma unroll
    for (int off = 32; off > 0; off >>= 1) v += __shfl_down(v, off, 64);
    return v;
}

__global__ __launch_bounds__(256) void pack_x_sums(const int* __restrict__ x,
                                                   signed char* __restrict__ x8,
                                                   const signed char* __restrict__ yt,
                                                   int* __restrict__ rowsum,
                                                   int* __restrict__ colsum) {
    int wave = threadIdx.x >> 6, lane = threadIdx.x & 63;
    int row = blockIdx.x * 4 + wave;
    if (row < (int)(GBn * M)) {
        const int* src = x + (size_t)row * K + lane * 16;   // 16 ints = 64B per lane
        int s = 0;
        uint32_t p[4];
#pragma unroll
        for (int q = 0; q < 4; ++q) {
            int4 v = ((const int4*)src)[q];
            s += v.x + v.y + v.z + v.w;
            p[q] =  (uint32_t)(v.x & 255)
                 | ((uint32_t)(v.y & 255) << 8)
                 | ((uint32_t)(v.z & 255) << 16)
                 | ((uint32_t)(v.w & 255) << 24);
        }
        *(uint4*)(x8 + (size_t)row * K + lane * 16) = make_uint4(p[0], p[1], p[2], p[3]);
        s = wave_reduce_sum(s);
        if (lane == 0) rowsum[row] = s;
    } else {
        int rr = row - (int)(GBn * M);                      // 0..4095  (b*N + n)
        uint4 u = *(const uint4*)(yt + (size_t)rr * K + lane * 16);
        uint32_t wds[4] = {u.x, u.y, u.z, u.w};
        int s = 0;
#pragma unroll
        for (int q = 0; q < 4; ++q) {
            uint32_t w = wds[q];
            s += (int)(signed char)(w) + (int)(signed char)(w >> 8)
               + (int)(signed char)(w >> 16) + (int)(signed char)(w >> 24);
        }
        s = wave_reduce_sum(s);
        if (lane == 0) colsum[rr] = s;
    }
}

// ---------------------------------------------------------------------------
// K3: i8 MFMA GEMM, restructured K-loop.
//   * A fragments load DIRECTLY from global x8 to VGPRs (row-major,
//     k-contiguous 16B per lane) — not in the barrier drain set, no LDS cost.
//   * B tile (128n x 64k, 8 KB) double-buffered in LDS via global_load_lds;
//     next-step stage issued right after the single per-step barrier, so it
//     has the whole MFMA sequence to land before the next drain.
//   * B slot-swizzle (verified R3): phys slot p of row r holds global chunk
//     p ^ ((r>>1)&3); staged by permuting the source chunk per lane.
// Block = 128x128 C-tile, 4 waves x (4x4 of 16x16x64 i8 MFMA).
// Grid: (M/128, N/128, 56).  __launch_bounds__(256,4) -> <=128 VGPR, 16 waves/CU.
// ---------------------------------------------------------------------------
__global__ __launch_bounds__(256, 4) void gemm_i8(const signed char* __restrict__ x8,
                                                  const signed char* __restrict__ yt,
                                                  const int* __restrict__ rowsum,
                                                  const int* __restrict__ colsum,
                                                  const float* __restrict__ xsp,
                                                  const float* __restrict__ ysp,
                                                  float* __restrict__ out) {
    __shared__ signed char Bs[2][128 * 64];     // double-buffered B [n][k]

    int mt = blockIdx.x;                        // 0..3
    int nt = blockIdx.y;                        // 0..3
    int gb = blockIdx.z;                        // 0..55
    int b  = gb & 7;
    int tid = threadIdx.x, wave = tid >> 6, lane = tid & 63;
    int wm = (wave >> 1) * 64, wn = (wave & 1) * 64;
    int fr = lane & 15;                         // row-in-tile (A) / col-in-tile (B)
    int q  = lane >> 4;                         // k-quad 0..3

    // B staging: 256 threads x 2 issues cover 128 rows x 64B. Wave w, issue c
    // stages rows c*64 + w*16 + (lane>>2); source chunk swizzled per lane.
    int srow  = lane >> 2;
    int sslot = (lane & 3) ^ ((lane >> 3) & 3);
    const signed char* Bb = yt + ((size_t)(b * N + nt * 128 + wave * 16 + srow)) * K + sslot * 16;

    // A direct: af[i] = 16 rows (wm+i*16+fr) x 16B at k0 + q*16
    const signed char* Aq = x8 + ((size_t)(gb * M + mt * 128 + wm + fr)) * K + q * 16;

    // swizzled read slot for B
    int fkB = (q ^ ((fr >> 1) & 3)) * 16;

    v4i acc[4][4];
#pragma unroll
    for (int i = 0; i < 4; ++i)
#pragma unroll
        for (int j = 0; j < 4; ++j) acc[i][j] = (v4i){0, 0, 0, 0};

    // prologue: stage k-step 0 into buf 0
#pragma unroll
    for (int c = 0; c < 2; ++c)
        __builtin_amdgcn_global_load_lds((const AS1 uint32_t*)(Bb + (size_t)c * 64 * K),
                                         (AS3 uint32_t*)(&Bs[0][0] + c * 4096 + wave * 1024), 16, 0, 0);

    for (int step = 0; step < 16; ++step) {
        int k0  = step * 64;
        int cur = step & 1;
        __syncthreads();                        // drains stage of buf[cur]; readers of buf[cur^1] done
        if (step < 15) {
#pragma unroll
            for (int c = 0; c < 2; ++c)
                __builtin_amdgcn_global_load_lds((const AS1 uint32_t*)(Bb + (size_t)c * 64 * K + k0 + 64),
                                                 (AS3 uint32_t*)(&Bs[cur ^ 1][0] + c * 4096 + wave * 1024), 16, 0, 0);
        }
        v4i af[4], bf[4];
#pragma unroll
        for (int i = 0; i < 4; ++i)
            af[i] = *(const v4i*)(Aq + (size_t)i * 16 * K + k0);
#pragma unroll
        for (int j = 0; j < 4; ++j)
            bf[j] = *(const v4i*)(&Bs[cur][0] + (wn + j * 16 + fr) * 64 + fkB);
#pragma unroll
        for (int i = 0; i < 4; ++i)
#pragma unroll
            for (int j = 0; j < 4; ++j)
                acc[i][j] = __builtin_amdgcn_mfma_i32_16x16x64_i8(af[i], bf[j], acc[i][j], 0, 0, 0);
    }

    // epilogue: C = s * (dot - 32*rowsum_x + 66*colsum_y' - 2162688)
    float s = xsp[0] * ysp[0];
    int colL = lane & 15;
    int rowQ = (lane >> 4) * 4;
    float* outg = out + (size_t)gb * M * N;
    const int* rs = rowsum + gb * M;
    const int* cs = colsum + b * N;
#pragma unroll
    for (int i = 0; i < 4; ++i) {
#pragma unroll
        for (int r = 0; r < 4; ++r) {
            int row_g = mt * 128 + wm + i * 16 + rowQ + r;
            int rsv = rs[row_g];
#pragma unroll
            for (int j = 0; j < 4; ++j) {
                int col_g = nt * 128 + wn + j * 16 + colL;
                int t = acc[i][j][r] - 32 * rsv + 66 * cs[col_g] - 2162688;
                outg[(size_t)row_g * N + col_g] = s * (float)t;
            }
        }
    }
}

// ---------------------------------------------------------------------------
// Fallback (only if ws_size is too small): naive but correct.
// sum (x-X)(y-Y) = dot(x,y) - 160*sum_x + 66*sum_y - 10,813,440
// ---------------------------------------------------------------------------
__global__ __launch_bounds__(256) void naive_kernel(const int* __restrict__ x,
                                                    const int* __restrict__ y,
                                                    const float* __restrict__ xsp,
                                                    const float* __restrict__ ysp,
                                                    float* __restrict__ out) {
    size_t idx = (size_t)blockIdx.x * 256 + threadIdx.x;   // over 14,680,064
    int n  = (int)(idx & 511);
    int m  = (int)((idx >> 9) & 511);
    int gb = (int)(idx >> 18);
    int b  = gb & 7;
    const int* xr = x + ((size_t)gb * M + m) * K;
    const int* yc = y + (size_t)b * K * N + n;
    int dot = 0, sx = 0, sy = 0;
    for (int k = 0; k < K; ++k) {
        int a = xr[k];
        int c = yc[(size_t)k * N];
        dot += a * c; sx += a; sy += c;
    }
    float s = xsp[0] * ysp[0];
    out[idx] = s * (float)(dot - 160 * sx + 66 * sy - 10813440);
}

// ---------------------------------------------------------------------------
extern "C" void kernel_launch(void* const* d_in, const int* in_sizes, int n_in,
                              void* d_out, int out_size, void* d_ws, size_t ws_size,
                              hipStream_t stream) {
    const int*   x  = (const int*)d_in[0];     // [7,8,512,1024] int8 values in int32
    const int*   y  = (const int*)d_in[1];     // [8,1024,512] uint8 values in int32
    const float* xs = (const float*)d_in[2];
    const float* ys = (const float*)d_in[3];
    float* out = (float*)d_out;

    if (ws_size < WS_NEEDED) {
        naive_kernel<<<(14680064 + 255) / 256, 256, 0, stream>>>(x, y, xs, ys, out);
        return;
    }

    char* ws = (char*)d_ws;
    signed char* x8 = (signed char*)ws;
    signed char* yt = (signed char*)(ws + X8_BYTES);
    int* rowsum = (int*)(ws + X8_BYTES + YT_BYTES);
    int* colsum = rowsum + RS_CNT;

    transpose_pack_y<<<dim3(N / 64, K / 64, B), 256, 0, stream>>>(y, yt);
    // 32768 rows total (28672 x-rows + 4096 yt-rows), 4 rows per block
    pack_x_sums<<<(GBn * M + CS_CNT) / 4, 256, 0, stream>>>(x, x8, yt, rowsum, colsum);
    gemm_i8<<<dim3(M / 128, N / 128, GBn), 256, 0, stream>>>(x8, yt, rowsum, colsum, xs, ys, out);
}

// Round 5
// 228.286 us; speedup vs baseline: 1.0574x; 1.0574x over previous
//
#include <hip/hip_runtime.h>
#include <stdint.h>

#define AS1 __attribute__((address_space(1)))
#define AS3 __attribute__((address_space(3)))

typedef int v4i __attribute__((ext_vector_type(4)));

// Problem constants (from reference)
constexpr int G = 7, B = 8, M = 512, N = 512, K = 1024;
constexpr int GBn = G * B;                       // 56
// X_ZP = -66, Y_ZP = 160.  With y' = y - 128:
//   sum (x-X)(y-Y) = dot_i8(x, y') - 32*rowsum_x + 66*colsum_y' - 2162688

// ws layout: only yt + colsum now (x8 pack pass eliminated)
constexpr size_t YT_BYTES = (size_t)B * N * K;   // 4,194,304  y transposed [b][n][k] i8 (y-128)
constexpr size_t CS_CNT   = (size_t)B * N;       // 4,096 colsums
constexpr size_t WS_NEEDED = YT_BYTES + CS_CNT * 4;

// ---------------------------------------------------------------------------
// K1: transpose + pack y:  y[b][k][n] (int32, 0..255)  ->  yt[b][n][k] (int8, y-128)
// 64x64 tiles through LDS. Grid: (N/64, K/64, B), block 256.
// ---------------------------------------------------------------------------
__global__ __launch_bounds__(256) void transpose_pack_y(const int* __restrict__ y,
                                                        signed char* __restrict__ yt) {
    __shared__ unsigned char tile[64][80];
    int n0 = blockIdx.x * 64;
    int k0 = blockIdx.y * 64;
    int b  = blockIdx.z;
    int t  = threadIdx.x;

    int r  = t >> 2;                              // k-local 0..63
    int c0 = (t & 3) * 16;                        // n-local byte offset
    const int* src = y + ((size_t)b * K + k0 + r) * N + n0 + c0;
    uint32_t p[4];
#pragma unroll
    for (int q = 0; q < 4; ++q) {
        int4 v = ((const int4*)src)[q];
        p[q] =  (uint32_t)((v.x & 255) ^ 128)
             | ((uint32_t)((v.y & 255) ^ 128) << 8)
             | ((uint32_t)((v.z & 255) ^ 128) << 16)
             | ((uint32_t)((v.w & 255) ^ 128) << 24);
    }
    *(uint4*)&tile[r][c0] = make_uint4(p[0], p[1], p[2], p[3]);
    __syncthreads();

    int nl = t >> 2;                              // n-local 0..63
    int kc = (t & 3) * 16;                        // k-local byte offset
    uint32_t q[4];
#pragma unroll
    for (int w = 0; w < 4; ++w) {
        uint32_t b0 = tile[kc + w * 4 + 0][nl];
        uint32_t b1 = tile[kc + w * 4 + 1][nl];
        uint32_t b2 = tile[kc + w * 4 + 2][nl];
        uint32_t b3 = tile[kc + w * 4 + 3][nl];
        q[w] = b0 | (b1 << 8) | (b2 << 16) | (b3 << 24);
    }
    *(uint4*)(yt + ((size_t)b * N + n0 + nl) * K + k0 + kc) = make_uint4(q[0], q[1], q[2], q[3]);
}

// ---------------------------------------------------------------------------
// K2 (tiny): colsum of yt. One wave per n-row (1024 i8). Grid 1024 x 256.
// ---------------------------------------------------------------------------
__global__ __launch_bounds__(256) void colsum_y(const signed char* __restrict__ yt,
                                                int* __restrict__ colsum) {
    int wave = threadIdx.x >> 6, lane = threadIdx.x & 63;
    int rr = blockIdx.x * 4 + wave;               // 0..4095 (b*N + n)
    uint4 u = *(const uint4*)(yt + (size_t)rr * K + lane * 16);
    uint32_t wds[4] = {u.x, u.y, u.z, u.w};
    int s = 0;
#pragma unroll
    for (int q = 0; q < 4; ++q) {
        uint32_t w = wds[q];
        s += (int)(signed char)(w) + (int)(signed char)(w >> 8)
           + (int)(signed char)(w >> 16) + (int)(signed char)(w >> 24);
    }
#pragma unroll
    for (int off = 32; off > 0; off >>= 1) s += __shfl_down(s, off, 64);
    if (lane == 0) colsum[rr] = s;
}

// ---------------------------------------------------------------------------
// K3: fused pack+GEMM. Block = 128m x 256n C-tile for one (g,b); 512 threads,
// 8 waves x (64x64 wave-tile: 4x4 of 16x16x64 i8 MFMA). BK=64, 16 steps.
//   * A: x int32 read DIRECTLY (each stripe read by the 2 n-blocks; 2nd is
//     L2/LLC), packed in-register to i8 (thread t: row t>>2, 64B -> 16B,
//     one ds_write_b128), double-buffered. rowsum accumulated during packing.
//   * B: yt staged via global_load_lds (16B), double-buffered.
//   * One barrier per step. Issue order after barrier: x-loads(s+1) FIRST,
//     then B-stage(s+1) — so the x vmcnt-wait (before pack) leaves the
//     B-stage in flight; pack runs after the MFMAs.
//   * Bit-exact LDS slot swizzle (verified R3): phys 16B slot p of row r
//     holds k-chunk p ^ ((r>>1)&3).
// Grid: (M/128, N/256, 56). launch_bounds(512,4) -> <=128 VGPR, 2 blocks/CU.
// ---------------------------------------------------------------------------
__global__ __launch_bounds__(512, 4) void gemm_i8(const int* __restrict__ x,
                                                  const signed char* __restrict__ yt,
                                                  const int* __restrict__ colsum,
                                                  const float* __restrict__ xsp,
                                                  const float* __restrict__ ysp,
                                                  float* __restrict__ out) {
    __shared__ signed char As[2][128 * 64];   // 16 KB
    __shared__ signed char Bs[2][256 * 64];   // 32 KB
    __shared__ int rsm[128];

    int mt = blockIdx.x;                      // 0..3
    int nt = blockIdx.y;                      // 0..1
    int gb = blockIdx.z;                      // 0..55
    int b  = gb & 7;
    int tid = threadIdx.x, wave = tid >> 6, lane = tid & 63;
    int wm = (wave >> 2) * 64, wn = (wave & 3) * 64;

    // x source: thread t handles A row (t>>2), k-chunk (t&3)*16 ints of each step
    int arow = tid >> 2;
    const int* xr = x + ((size_t)(gb * M + mt * 128 + arow)) * K + (tid & 3) * 16;
    // A ds_write dest: swizzled 16B slot
    int aslot = (tid & 3) ^ ((arow >> 1) & 3);
    int aoff  = arow * 64 + aslot * 16;

    // B staging: issue c in {0,1}: wave-uniform LDS base c*8192 + wave*1024
    // covers rows c*128 + wave*16 .. +15; lane -> row +(lane>>2), swizzled chunk
    int bslot = (lane & 3) ^ ((lane >> 3) & 3);
    const signed char* Bb = yt + ((size_t)(b * N + nt * 256 + wave * 16 + (lane >> 2))) * K + bslot * 16;

    // fragment read offsets (swizzle key = (fr>>1)&3 since tile bases are %16==0)
    int fr = lane & 15, q = lane >> 4;
    int fko = (q ^ ((fr >> 1) & 3)) * 16;

    v4i acc[4][4];
#pragma unroll
    for (int i = 0; i < 4; ++i)
#pragma unroll
        for (int j = 0; j < 4; ++j) acc[i][j] = (v4i){0, 0, 0, 0};

    int rs_part = 0;

    // ---- prologue: step 0 ----
    int4 xv[4];
#pragma unroll
    for (int h = 0; h < 4; ++h) xv[h] = ((const int4*)xr)[h];
#pragma unroll
    for (int c = 0; c < 2; ++c)
        __builtin_amdgcn_global_load_lds((const AS1 uint32_t*)(Bb + (size_t)c * 128 * K),
                                         (AS3 uint32_t*)(&Bs[0][0] + c * 8192 + wave * 1024), 16, 0, 0);
    {
        uint32_t pw[4];
#pragma unroll
        for (int h = 0; h < 4; ++h) {
            int4 v = xv[h];
            rs_part += v.x + v.y + v.z + v.w;
            pw[h] =  (uint32_t)(v.x & 255) | ((uint32_t)(v.y & 255) << 8)
                  | ((uint32_t)(v.z & 255) << 16) | ((uint32_t)(v.w & 255) << 24);
        }
        *(uint4*)(&As[0][0] + aoff) = make_uint4(pw[0], pw[1], pw[2], pw[3]);
    }

    for (int s = 0; s < 16; ++s) {
        int cur = s & 1;
        __syncthreads();          // drains B-stage(s) [issued a full step ago] + A pack(s)

        int4 xn[4];
        if (s < 15) {
            const int* xs_ = xr + (s + 1) * 64;
#pragma unroll
            for (int h = 0; h < 4; ++h) xn[h] = ((const int4*)xs_)[h];   // vmem, waited at pack
#pragma unroll
            for (int c = 0; c < 2; ++c)
                __builtin_amdgcn_global_load_lds((const AS1 uint32_t*)(Bb + (size_t)c * 128 * K + (s + 1) * 64),
                                                 (AS3 uint32_t*)(&Bs[cur ^ 1][0] + c * 8192 + wave * 1024), 16, 0, 0);
        }

        v4i af[4], bf[4];
#pragma unroll
        for (int i = 0; i < 4; ++i)
            af[i] = *(const v4i*)(&As[cur][0] + (wm + i * 16 + fr) * 64 + fko);
#pragma unroll
        for (int j = 0; j < 4; ++j)
            bf[j] = *(const v4i*)(&Bs[cur][0] + (wn + j * 16 + fr) * 64 + fko);
#pragma unroll
        for (int i = 0; i < 4; ++i)
#pragma unroll
            for (int j = 0; j < 4; ++j)
                acc[i][j] = __builtin_amdgcn_mfma_i32_16x16x64_i8(af[i], bf[j], acc[i][j], 0, 0, 0);

        if (s < 15) {
            uint32_t pw[4];
#pragma unroll
            for (int h = 0; h < 4; ++h) {
                int4 v = xn[h];
                rs_part += v.x + v.y + v.z + v.w;
                pw[h] =  (uint32_t)(v.x & 255) | ((uint32_t)(v.y & 255) << 8)
                      | ((uint32_t)(v.z & 255) << 16) | ((uint32_t)(v.w & 255) << 24);
            }
            *(uint4*)(&As[cur ^ 1][0] + aoff) = make_uint4(pw[0], pw[1], pw[2], pw[3]);
        }
    }

    // rowsum: 4 threads per row (tid&3 = k-chunk) -> reduce, broadcast via LDS
    rs_part += __shfl_down(rs_part, 1, 64);
    rs_part += __shfl_down(rs_part, 2, 64);
    if ((lane & 3) == 0) rsm[arow] = rs_part;
    __syncthreads();

    // epilogue: C = s * (dot - 32*rowsum_x + 66*colsum_y' - 2162688)
    float sc = xsp[0] * ysp[0];
    int colL = lane & 15;
    int rowQ = (lane >> 4) * 4;
    float* outg = out + (size_t)gb * M * N;
    const int* cs = colsum + b * N;
#pragma unroll
    for (int i = 0; i < 4; ++i) {
#pragma unroll
        for (int r = 0; r < 4; ++r) {
            int row_l = wm + i * 16 + rowQ + r;               // 0..127 within block
            int row_g = mt * 128 + row_l;
            int rsv = rsm[row_l];
#pragma unroll
            for (int j = 0; j < 4; ++j) {
                int col_g = nt * 256 + wn + j * 16 + colL;
                int t = acc[i][j][r] - 32 * rsv + 66 * cs[col_g] - 2162688;
                outg[(size_t)row_g * N + col_g] = sc * (float)t;
            }
        }
    }
}

// ---------------------------------------------------------------------------
// Fallback (only if ws_size is too small): naive but correct.
// sum (x-X)(y-Y) = dot(x,y) - 160*sum_x + 66*sum_y - 10,813,440
// ---------------------------------------------------------------------------
__global__ __launch_bounds__(256) void naive_kernel(const int* __restrict__ x,
                                                    const int* __restrict__ y,
                                                    const float* __restrict__ xsp,
                                                    const float* __restrict__ ysp,
                                                    float* __restrict__ out) {
    size_t idx = (size_t)blockIdx.x * 256 + threadIdx.x;   // over 14,680,064
    int n  = (int)(idx & 511);
    int m  = (int)((idx >> 9) & 511);
    int gb = (int)(idx >> 18);
    int b  = gb & 7;
    const int* xr = x + ((size_t)gb * M + m) * K;
    const int* yc = y + (size_t)b * K * N + n;
    int dot = 0, sx = 0, sy = 0;
    for (int k = 0; k < K; ++k) {
        int a = xr[k];
        int c = yc[(size_t)k * N];
        dot += a * c; sx += a; sy += c;
    }
    float s = xsp[0] * ysp[0];
    out[idx] = s * (float)(dot - 160 * sx + 66 * sy - 10813440);
}

// ---------------------------------------------------------------------------
extern "C" void kernel_launch(void* const* d_in, const int* in_sizes, int n_in,
                              void* d_out, int out_size, void* d_ws, size_t ws_size,
                              hipStream_t stream) {
    const int*   x  = (const int*)d_in[0];     // [7,8,512,1024] int8 values in int32
    const int*   y  = (const int*)d_in[1];     // [8,1024,512] uint8 values in int32
    const float* xs = (const float*)d_in[2];
    const float* ys = (const float*)d_in[3];
    float* out = (float*)d_out;

    if (ws_size < WS_NEEDED) {
        naive_kernel<<<(14680064 + 255) / 256, 256, 0, stream>>>(x, y, xs, ys, out);
        return;
    }

    char* ws = (char*)d_ws;
    signed char* yt = (signed char*)ws;
    int* colsum = (int*)(ws + YT_BYTES);

    transpose_pack_y<<<dim3(N / 64, K / 64, B), 256, 0, stream>>>(y, yt);
    colsum_y<<<(B * N) / 4, 256, 0, stream>>>(yt, colsum);
    gemm_i8<<<dim3(M / 128, N / 256, GBn), 512, 0, stream>>>(x, yt, colsum, xs, ys, out);
}